// Round 1
// baseline (203.286 us; speedup 1.0000x reference)
//
#include <hip/hip_runtime.h>

#define NB 128
#define NA 2
#define NH 128
#define NW 128
#define PLANE (NH * NW)            // 16384
#define RTHRESH 0.6f
#define OBJ_SCALE 5.0f

__device__ __forceinline__ float sigm(float v) {
    return 1.0f / (1.0f + __expf(-v));
}

// Per-batch GT-box constants + best-anchor selection (pure arithmetic from
// target/anchors; recomputed wherever needed — inputs are tiny and L1-hit).
__device__ __forceinline__ void batch_const(const float* __restrict__ target,
                                            const float* __restrict__ anchors,
                                            int b,
                                            float& gx, float& gy, float& gw, float& gh,
                                            int& bn, int& gxi, int& gyi) {
    float t0 = target[b * 4 + 0], t1 = target[b * 4 + 1];
    float t2 = target[b * 4 + 2], t3 = target[b * 4 + 3];
    gx = t0 * (float)NW;
    gy = t1 * (float)NH;
    gw = t2 * (float)NW;
    gh = t3 * (float)NH;
    float a0w = anchors[0], a0h = anchors[1];
    float a1w = anchors[2], a1h = anchors[3];
    float i0 = fminf(gw, a0w) * fminf(gh, a0h);
    float u0 = gw * gh + 1e-16f + a0w * a0h - i0;
    float i1 = fminf(gw, a1w) * fminf(gh, a1h);
    float u1 = gw * gh + 1e-16f + a1w * a1h - i1;
    // argmax picks the FIRST max: anchor 1 only on strict greater.
    bn  = (i1 / u1 > i0 / u0) ? 1 : 0;
    gxi = (int)gx;   // gt_x in (12.8, 115.2) so trunc == floor, in-bounds
    gyi = (int)gy;
}

// Dense pass: every (b, a, i, j) cell — IoU vs GT, noobj mask, accumulate
// sum(conf^2 masked) and count(masked). One float4 group (4 cells) / thread.
__global__ __launch_bounds__(256) void region_main(
        const float* __restrict__ out,
        const float* __restrict__ target,
        const float* __restrict__ anchors,
        double* __restrict__ ws_sum,
        unsigned long long* __restrict__ ws_cnt) {
    int idx4 = blockIdx.x * 256 + threadIdx.x;   // 0 .. 2^20-1
    int j0 = (idx4 & 31) * 4;                    // 4-aligned column
    int i  = (idx4 >> 5) & 127;
    int a  = (idx4 >> 12) & 1;
    int b  = idx4 >> 13;

    float gx, gy, gw, gh; int bn, gxi, gyi;
    batch_const(target, anchors, b, gx, gy, gw, gh, bn, gxi, gyi);

    float aw = anchors[a * 2 + 0];
    float ah = anchors[a * 2 + 1];

    size_t base = (size_t)(b * 10 + a * 5) * PLANE + (size_t)i * NW + (size_t)j0;
    float4 vx = *(const float4*)(out + base);
    float4 vy = *(const float4*)(out + base + 1 * PLANE);
    float4 vw = *(const float4*)(out + base + 2 * PLANE);
    float4 vh = *(const float4*)(out + base + 3 * PLANE);
    float4 vc = *(const float4*)(out + base + 4 * PLANE);

    float gxm = gx - gw * 0.5f, gxM = gx + gw * 0.5f;
    float gym = gy - gh * 0.5f, gyM = gy + gh * 0.5f;
    float garea = gw * gh;
    bool row_sel = (a == bn) && (i == gyi);

    float lsum = 0.0f;
    int   lcnt = 0;

    const float* px4 = (const float*)&vx;
    const float* py4 = (const float*)&vy;
    const float* pw4 = (const float*)&vw;
    const float* ph4 = (const float*)&vh;
    const float* pc4 = (const float*)&vc;

#pragma unroll
    for (int e = 0; e < 4; ++e) {
        float px = sigm(px4[e]) + (float)(j0 + e);
        float py = sigm(py4[e]) + (float)i;
        float pw = __expf(pw4[e]) * aw;
        float ph = __expf(ph4[e]) * ah;
        float cf = sigm(pc4[e]);

        float mx = fminf(px - pw * 0.5f, gxm);
        float Mx = fmaxf(px + pw * 0.5f, gxM);
        float my = fminf(py - ph * 0.5f, gym);
        float My = fmaxf(py + ph * 0.5f, gyM);
        float cw = pw + gw - (Mx - mx);
        float ch = ph + gh - (My - my);
        float iou = 0.0f;
        if (cw > 0.0f && ch > 0.0f) {
            float carea = cw * ch;
            iou = carea / (pw * ph + garea - carea);
        }
        bool noobj = (iou <= RTHRESH) && !(row_sel && (j0 + e) == gxi);
        if (noobj) { lsum += cf * cf; lcnt += 1; }
    }

    // wave64 shuffle reduce, then LDS across the 4 waves
#pragma unroll
    for (int off = 32; off > 0; off >>= 1) {
        lsum += __shfl_down(lsum, off);
        lcnt += __shfl_down(lcnt, off);
    }
    __shared__ float ssum[4];
    __shared__ int   scnt[4];
    int wid = threadIdx.x >> 6, lane = threadIdx.x & 63;
    if (lane == 0) { ssum[wid] = lsum; scnt[wid] = lcnt; }
    __syncthreads();
    if (threadIdx.x == 0) {
        float s = ssum[0] + ssum[1] + ssum[2] + ssum[3];
        int   c = scnt[0] + scnt[1] + scnt[2] + scnt[3];
        atomicAdd(ws_sum, (double)s);
        atomicAdd(ws_cnt, (unsigned long long)c);
    }
}

// Epilogue: per-batch selected-cell losses + final combine. 1 block, 128 thr.
__global__ __launch_bounds__(128) void region_final(
        const float* __restrict__ out,
        const float* __restrict__ target,
        const float* __restrict__ anchors,
        const double* __restrict__ ws_sum,
        const unsigned long long* __restrict__ ws_cnt,
        float* __restrict__ loss_out) {
    int b = threadIdx.x;   // 0..127

    float gx, gy, gw, gh; int bn, gxi, gyi;
    batch_const(target, anchors, b, gx, gy, gw, gh, bn, gxi, gyi);

    float tx = gx - floorf(gx);
    float ty = gy - floorf(gy);
    float aw = anchors[bn * 2 + 0];
    float ah = anchors[bn * 2 + 1];
    float tw = __logf(gw / aw + 1e-16f);
    float th = __logf(gh / ah + 1e-16f);
    float scale = 2.0f - target[b * 4 + 2] * target[b * 4 + 3];

    size_t base = (size_t)(b * 10 + bn * 5) * PLANE + (size_t)gyi * NW + (size_t)gxi;
    float xs = sigm(out[base]);
    float ys = sigm(out[base + 1 * PLANE]);
    float wr = out[base + 2 * PLANE];          // raw, no sigmoid
    float hr = out[base + 3 * PLANE];
    float cs = sigm(out[base + 4 * PLANE]);

    float dx = xs * scale - tx * scale;
    float dy = ys * scale - ty * scale;
    float dw = wr * scale - tw * scale;
    float dh = hr * scale - th * scale;
    float dc = cs - 1.0f;
    float v = dx * dx + dy * dy + dw * dw + dh * dh + OBJ_SCALE * dc * dc;

#pragma unroll
    for (int off = 32; off > 0; off >>= 1) v += __shfl_down(v, off);
    __shared__ float s2[2];
    if ((threadIdx.x & 63) == 0) s2[threadIdx.x >> 6] = v;
    __syncthreads();
    if (threadIdx.x == 0) {
        float per_batch = (s2[0] + s2[1]) * (1.0f / (float)NB);
        double sc  = *ws_sum;
        double cnt = (double)(*ws_cnt);
        loss_out[0] = per_batch + (float)(sc / cnt);
    }
}

extern "C" void kernel_launch(void* const* d_in, const int* in_sizes, int n_in,
                              void* d_out, int out_size, void* d_ws, size_t ws_size,
                              hipStream_t stream) {
    const float* output  = (const float*)d_in[0];   // (128, 10, 128, 128)
    const float* target  = (const float*)d_in[1];   // (128, 4)
    const float* anchors = (const float*)d_in[2];   // (2, 2)
    float* loss = (float*)d_out;

    double* ws_sum = (double*)d_ws;
    unsigned long long* ws_cnt = (unsigned long long*)((char*)d_ws + 8);

    // d_ws is re-poisoned 0xAA before every timed launch — zero accumulators.
    hipMemsetAsync(d_ws, 0, 16, stream);

    // 4096 blocks x 256 threads x (4 cells/thread) == 4,194,304 cells, exact.
    region_main<<<4096, 256, 0, stream>>>(output, target, anchors, ws_sum, ws_cnt);
    region_final<<<1, 128, 0, stream>>>(output, target, anchors, ws_sum, ws_cnt, loss);
}

// Round 2
// 124.934 us; speedup vs baseline: 1.6272x; 1.6272x over previous
//
#include <hip/hip_runtime.h>

#define NB 128
#define NA 2
#define NH 128
#define NW 128
#define PLANE (NH * NW)            // 16384 floats per channel plane
#define RTHRESH 0.6f
#define OBJ_SCALE 5.0f
#define NBLK 1024                  // main-pass blocks (4 per slab, 4/CU)

__device__ __forceinline__ float sigm(float v) {
    return 1.0f / (1.0f + __expf(-v));
}

// Per-batch GT-box constants + best-anchor selection (tiny inputs, L1-hit,
// wave-uniform b -> compiler emits scalar loads).
__device__ __forceinline__ void batch_const(const float* __restrict__ target,
                                            const float* __restrict__ anchors,
                                            int b,
                                            float& gx, float& gy, float& gw, float& gh,
                                            int& bn, int& gxi, int& gyi) {
    float t0 = target[b * 4 + 0], t1 = target[b * 4 + 1];
    float t2 = target[b * 4 + 2], t3 = target[b * 4 + 3];
    gx = t0 * (float)NW;
    gy = t1 * (float)NH;
    gw = t2 * (float)NW;
    gh = t3 * (float)NH;
    float a0w = anchors[0], a0h = anchors[1];
    float a1w = anchors[2], a1h = anchors[3];
    float i0 = fminf(gw, a0w) * fminf(gh, a0h);
    float u0 = gw * gh + 1e-16f + a0w * a0h - i0;
    float i1 = fminf(gw, a1w) * fminf(gh, a1h);
    float u1 = gw * gh + 1e-16f + a1w * a1h - i1;
    bn  = (i1 / u1 > i0 / u0) ? 1 : 0;   // argmax picks FIRST max
    gxi = (int)gx;   // gt_x in (12.8, 115.2): trunc == floor, in-bounds
    gyi = (int)gy;
}

// Dense pass. 1024 blocks x 256 threads x 16 cells = 4,194,304 cells.
// Block bid: slab = bid>>2 ((b,a) pair), quarter q = bid&3 (4096 cells).
// All 20 float4 loads issued before any compute -> 20 KB in flight per wave.
// Per-block partial sum/count -> d_ws arrays (no atomics, no memset needed).
__global__ __launch_bounds__(256) void region_main(
        const float* __restrict__ out,
        const float* __restrict__ target,
        const float* __restrict__ anchors,
        float* __restrict__ psum,
        unsigned int* __restrict__ pcnt) {
    int bid = blockIdx.x, tid = threadIdx.x;
    int slab = bid >> 2, q = bid & 3;
    int b = slab >> 1, a = slab & 1;

    float gx, gy, gw, gh; int bn, gxi, gyi;
    batch_const(target, anchors, b, gx, gy, gw, gh, bn, gxi, gyi);
    float aw = anchors[a * 2 + 0];
    float ah = anchors[a * 2 + 1];

    const float* pb = out + (size_t)(b * 10 + a * 5) * PLANE + q * 4096 + tid * 4;

    float4 vx[4], vy[4], vw[4], vh[4], vc[4];
#pragma unroll
    for (int it = 0; it < 4; ++it) {
        const float* p = pb + it * 1024;
        vx[it] = *(const float4*)(p);
        vy[it] = *(const float4*)(p + 1 * PLANE);
        vw[it] = *(const float4*)(p + 2 * PLANE);
        vh[it] = *(const float4*)(p + 3 * PLANE);
        vc[it] = *(const float4*)(p + 4 * PLANE);
    }

    float gxm = gx - gw * 0.5f, gxM = gx + gw * 0.5f;
    float gym = gy - gh * 0.5f, gyM = gy + gh * 0.5f;
    float garea = gw * gh;
    bool a_sel = (a == bn);

    float lsum = 0.0f;
    int   lcnt = 0;

#pragma unroll
    for (int it = 0; it < 4; ++it) {
        const float* fx = (const float*)&vx[it];
        const float* fy = (const float*)&vy[it];
        const float* fw = (const float*)&vw[it];
        const float* fh = (const float*)&vh[it];
        const float* fc = (const float*)&vc[it];
        int pos0 = q * 4096 + it * 1024 + tid * 4;
#pragma unroll
        for (int e = 0; e < 4; ++e) {
            int pos = pos0 + e;
            int j = pos & 127, i = pos >> 7;
            float px = sigm(fx[e]) + (float)j;
            float py = sigm(fy[e]) + (float)i;
            float pw = __expf(fw[e]) * aw;
            float ph = __expf(fh[e]) * ah;
            float cf = sigm(fc[e]);

            float mx = fminf(px - pw * 0.5f, gxm);
            float Mx = fmaxf(px + pw * 0.5f, gxM);
            float my = fminf(py - ph * 0.5f, gym);
            float My = fmaxf(py + ph * 0.5f, gyM);
            float cw = pw + gw - (Mx - mx);
            float ch = ph + gh - (My - my);
            float iou = 0.0f;
            if (cw > 0.0f && ch > 0.0f) {
                float carea = cw * ch;
                iou = carea / (pw * ph + garea - carea);
            }
            bool noobj = (iou <= RTHRESH) && !(a_sel && i == gyi && j == gxi);
            if (noobj) { lsum += cf * cf; lcnt += 1; }
        }
    }

    // wave64 shuffle tree, then LDS across 4 waves, one store per block
#pragma unroll
    for (int off = 32; off > 0; off >>= 1) {
        lsum += __shfl_down(lsum, off);
        lcnt += __shfl_down(lcnt, off);
    }
    __shared__ float ssum[4];
    __shared__ int   scnt[4];
    int wid = tid >> 6, lane = tid & 63;
    if (lane == 0) { ssum[wid] = lsum; scnt[wid] = lcnt; }
    __syncthreads();
    if (tid == 0) {
        psum[bid] = ssum[0] + ssum[1] + ssum[2] + ssum[3];
        pcnt[bid] = (unsigned int)(scnt[0] + scnt[1] + scnt[2] + scnt[3]);
    }
}

// Final: reduce 1024 partials + 128 selected-cell losses. 1 block, 1024 thr.
__global__ __launch_bounds__(1024) void region_final(
        const float* __restrict__ out,
        const float* __restrict__ target,
        const float* __restrict__ anchors,
        const float* __restrict__ psum,
        const unsigned int* __restrict__ pcnt,
        float* __restrict__ loss_out) {
    int t = threadIdx.x;
    float s = psum[t];
    unsigned int c = pcnt[t];

    float v = 0.0f;
    if (t < NB) {
        int b = t;
        float gx, gy, gw, gh; int bn, gxi, gyi;
        batch_const(target, anchors, b, gx, gy, gw, gh, bn, gxi, gyi);
        float tx = gx - floorf(gx);
        float ty = gy - floorf(gy);
        float aw = anchors[bn * 2 + 0];
        float ah = anchors[bn * 2 + 1];
        float tw = __logf(gw / aw + 1e-16f);
        float th = __logf(gh / ah + 1e-16f);
        float scale = 2.0f - target[b * 4 + 2] * target[b * 4 + 3];

        size_t base = (size_t)(b * 10 + bn * 5) * PLANE + (size_t)gyi * NW + (size_t)gxi;
        float xs = sigm(out[base]);
        float ys = sigm(out[base + 1 * PLANE]);
        float wr = out[base + 2 * PLANE];
        float hr = out[base + 3 * PLANE];
        float cs = sigm(out[base + 4 * PLANE]);

        float dx = (xs - tx) * scale;
        float dy = (ys - ty) * scale;
        float dw = (wr - tw) * scale;
        float dh = (hr - th) * scale;
        float dc = cs - 1.0f;
        v = dx * dx + dy * dy + dw * dw + dh * dh + OBJ_SCALE * dc * dc;
    }

#pragma unroll
    for (int off = 32; off > 0; off >>= 1) {
        s += __shfl_down(s, off);
        c += __shfl_down(c, off);
        v += __shfl_down(v, off);
    }
    __shared__ float ss[16];
    __shared__ unsigned int sc[16];
    __shared__ float sv[16];
    int wid = t >> 6, lane = t & 63;
    if (lane == 0) { ss[wid] = s; sc[wid] = c; sv[wid] = v; }
    __syncthreads();
    if (t < 16) {
        s = ss[t]; c = sc[t]; v = sv[t];
#pragma unroll
        for (int off = 8; off > 0; off >>= 1) {
            s += __shfl_down(s, off);
            c += __shfl_down(c, off);
            v += __shfl_down(v, off);
        }
        if (t == 0)
            loss_out[0] = v * (1.0f / (float)NB) + s / (float)c;
    }
}

extern "C" void kernel_launch(void* const* d_in, const int* in_sizes, int n_in,
                              void* d_out, int out_size, void* d_ws, size_t ws_size,
                              hipStream_t stream) {
    const float* output  = (const float*)d_in[0];   // (128, 10, 128, 128) fp32
    const float* target  = (const float*)d_in[1];   // (128, 4)
    const float* anchors = (const float*)d_in[2];   // (2, 2)
    float* loss = (float*)d_out;

    // d_ws layout: [0, 4096) float psum[1024]; [4096, 8192) uint pcnt[1024].
    // Every slot is written unconditionally -> no memset of poisoned ws needed.
    float* psum = (float*)d_ws;
    unsigned int* pcnt = (unsigned int*)((char*)d_ws + NBLK * sizeof(float));

    region_main<<<NBLK, 256, 0, stream>>>(output, target, anchors, psum, pcnt);
    region_final<<<1, 1024, 0, stream>>>(output, target, anchors, psum, pcnt, loss);
}

// Round 3
// 121.692 us; speedup vs baseline: 1.6705x; 1.0266x over previous
//
#include <hip/hip_runtime.h>

#define NB 128
#define NA 2
#define NH 128
#define NW 128
#define PLANE (NH * NW)            // 16384 floats per channel plane
#define RTHRESH 0.6f
#define OBJ_SCALE 5.0f
#define NBLK 4096                  // main-pass blocks, 4 cells/thread

__device__ __forceinline__ float sigm(float v) {
    return 1.0f / (1.0f + __expf(-v));
}

// Per-batch GT-box constants + best-anchor selection (tiny inputs, L1-hit,
// wave-uniform b -> compiler emits scalar loads).
__device__ __forceinline__ void batch_const(const float* __restrict__ target,
                                            const float* __restrict__ anchors,
                                            int b,
                                            float& gx, float& gy, float& gw, float& gh,
                                            int& bn, int& gxi, int& gyi) {
    float t0 = target[b * 4 + 0], t1 = target[b * 4 + 1];
    float t2 = target[b * 4 + 2], t3 = target[b * 4 + 3];
    gx = t0 * (float)NW;
    gy = t1 * (float)NH;
    gw = t2 * (float)NW;
    gh = t3 * (float)NH;
    float a0w = anchors[0], a0h = anchors[1];
    float a1w = anchors[2], a1h = anchors[3];
    float i0 = fminf(gw, a0w) * fminf(gh, a0h);
    float u0 = gw * gh + 1e-16f + a0w * a0h - i0;
    float i1 = fminf(gw, a1w) * fminf(gh, a1h);
    float u1 = gw * gh + 1e-16f + a1w * a1h - i1;
    bn  = (i1 / u1 > i0 / u0) ? 1 : 0;   // argmax picks FIRST max
    gxi = (int)gx;   // gt_x in (12.8, 115.2): trunc == floor, in-bounds
    gyi = (int)gy;
}

// Dense pass. 4096 blocks x 256 threads x 4 cells = 4,194,304 cells.
// Thin threads (5 float4 loads, low VGPR -> 8 blocks/CU resident) + per-block
// partial writes (NO same-address atomics — round-1 postmortem: 8192 same-line
// atomics serialized at ~30cyc each = ~85us, the entire round-1 bottleneck).
__global__ __launch_bounds__(256) void region_main(
        const float* __restrict__ out,
        const float* __restrict__ target,
        const float* __restrict__ anchors,
        float* __restrict__ psum,
        unsigned int* __restrict__ pcnt) {
    int tid = threadIdx.x;
    int idx4 = blockIdx.x * 256 + tid;           // 0 .. 2^20-1
    int j0 = (idx4 & 31) * 4;                    // 4-aligned column
    int i  = (idx4 >> 5) & 127;
    int a  = (idx4 >> 12) & 1;
    int b  = idx4 >> 13;

    float gx, gy, gw, gh; int bn, gxi, gyi;
    batch_const(target, anchors, b, gx, gy, gw, gh, bn, gxi, gyi);
    float aw = anchors[a * 2 + 0];
    float ah = anchors[a * 2 + 1];

    size_t base = (size_t)(b * 10 + a * 5) * PLANE + (size_t)i * NW + (size_t)j0;
    float4 vx = *(const float4*)(out + base);
    float4 vy = *(const float4*)(out + base + 1 * PLANE);
    float4 vw = *(const float4*)(out + base + 2 * PLANE);
    float4 vh = *(const float4*)(out + base + 3 * PLANE);
    float4 vc = *(const float4*)(out + base + 4 * PLANE);

    float gxm = gx - gw * 0.5f, gxM = gx + gw * 0.5f;
    float gym = gy - gh * 0.5f, gyM = gy + gh * 0.5f;
    float garea = gw * gh;
    bool row_sel = (a == bn) && (i == gyi);

    float lsum = 0.0f;
    int   lcnt = 0;

    const float* fx = (const float*)&vx;
    const float* fy = (const float*)&vy;
    const float* fw = (const float*)&vw;
    const float* fh = (const float*)&vh;
    const float* fc = (const float*)&vc;

#pragma unroll
    for (int e = 0; e < 4; ++e) {
        float px = sigm(fx[e]) + (float)(j0 + e);
        float py = sigm(fy[e]) + (float)i;
        float pw = __expf(fw[e]) * aw;
        float ph = __expf(fh[e]) * ah;
        float cf = sigm(fc[e]);

        float mx = fminf(px - pw * 0.5f, gxm);
        float Mx = fmaxf(px + pw * 0.5f, gxM);
        float my = fminf(py - ph * 0.5f, gym);
        float My = fmaxf(py + ph * 0.5f, gyM);
        float cw = pw + gw - (Mx - mx);
        float ch = ph + gh - (My - my);
        float iou = 0.0f;
        if (cw > 0.0f && ch > 0.0f) {
            float carea = cw * ch;
            iou = carea / (pw * ph + garea - carea);
        }
        bool noobj = (iou <= RTHRESH) && !(row_sel && (j0 + e) == gxi);
        if (noobj) { lsum += cf * cf; lcnt += 1; }
    }

    // wave64 shuffle tree, then LDS across 4 waves, one store per block
#pragma unroll
    for (int off = 32; off > 0; off >>= 1) {
        lsum += __shfl_down(lsum, off);
        lcnt += __shfl_down(lcnt, off);
    }
    __shared__ float ssum[4];
    __shared__ int   scnt[4];
    int wid = tid >> 6, lane = tid & 63;
    if (lane == 0) { ssum[wid] = lsum; scnt[wid] = lcnt; }
    __syncthreads();
    if (tid == 0) {
        psum[blockIdx.x] = ssum[0] + ssum[1] + ssum[2] + ssum[3];
        pcnt[blockIdx.x] = (unsigned int)(scnt[0] + scnt[1] + scnt[2] + scnt[3]);
    }
}

// Final: reduce 4096 partials + 128 selected-cell losses. 1 block, 1024 thr.
__global__ __launch_bounds__(1024) void region_final(
        const float* __restrict__ out,
        const float* __restrict__ target,
        const float* __restrict__ anchors,
        const float* __restrict__ psum,
        const unsigned int* __restrict__ pcnt,
        float* __restrict__ loss_out) {
    int t = threadIdx.x;
    float s = 0.0f;
    unsigned int c = 0;
#pragma unroll
    for (int k = 0; k < NBLK / 1024; ++k) {
        s += psum[t + k * 1024];
        c += pcnt[t + k * 1024];
    }

    float v = 0.0f;
    if (t < NB) {
        int b = t;
        float gx, gy, gw, gh; int bn, gxi, gyi;
        batch_const(target, anchors, b, gx, gy, gw, gh, bn, gxi, gyi);
        float tx = gx - floorf(gx);
        float ty = gy - floorf(gy);
        float aw = anchors[bn * 2 + 0];
        float ah = anchors[bn * 2 + 1];
        float tw = __logf(gw / aw + 1e-16f);
        float th = __logf(gh / ah + 1e-16f);
        float scale = 2.0f - target[b * 4 + 2] * target[b * 4 + 3];

        size_t base = (size_t)(b * 10 + bn * 5) * PLANE + (size_t)gyi * NW + (size_t)gxi;
        float xs = sigm(out[base]);
        float ys = sigm(out[base + 1 * PLANE]);
        float wr = out[base + 2 * PLANE];
        float hr = out[base + 3 * PLANE];
        float cs = sigm(out[base + 4 * PLANE]);

        float dx = (xs - tx) * scale;
        float dy = (ys - ty) * scale;
        float dw = (wr - tw) * scale;
        float dh = (hr - th) * scale;
        float dc = cs - 1.0f;
        v = dx * dx + dy * dy + dw * dw + dh * dh + OBJ_SCALE * dc * dc;
    }

#pragma unroll
    for (int off = 32; off > 0; off >>= 1) {
        s += __shfl_down(s, off);
        c += __shfl_down(c, off);
        v += __shfl_down(v, off);
    }
    __shared__ float ss[16];
    __shared__ unsigned int sc[16];
    __shared__ float sv[16];
    int wid = t >> 6, lane = t & 63;
    if (lane == 0) { ss[wid] = s; sc[wid] = c; sv[wid] = v; }
    __syncthreads();
    if (t < 16) {
        s = ss[t]; c = sc[t]; v = sv[t];
#pragma unroll
        for (int off = 8; off > 0; off >>= 1) {
            s += __shfl_down(s, off);
            c += __shfl_down(c, off);
            v += __shfl_down(v, off);
        }
        if (t == 0)
            loss_out[0] = v * (1.0f / (float)NB) + s / (float)c;
    }
}

extern "C" void kernel_launch(void* const* d_in, const int* in_sizes, int n_in,
                              void* d_out, int out_size, void* d_ws, size_t ws_size,
                              hipStream_t stream) {
    const float* output  = (const float*)d_in[0];   // (128, 10, 128, 128) fp32
    const float* target  = (const float*)d_in[1];   // (128, 4)
    const float* anchors = (const float*)d_in[2];   // (2, 2)
    float* loss = (float*)d_out;

    // d_ws layout: [0,16K) float psum[4096]; [16K,32K) uint pcnt[4096].
    // Every slot written unconditionally -> no memset of poisoned ws needed.
    float* psum = (float*)d_ws;
    unsigned int* pcnt = (unsigned int*)((char*)d_ws + NBLK * sizeof(float));

    region_main<<<NBLK, 256, 0, stream>>>(output, target, anchors, psum, pcnt);
    region_final<<<1, 1024, 0, stream>>>(output, target, anchors, psum, pcnt, loss);
}